// Round 1
// 121.491 us; speedup vs baseline: 1.0062x; 1.0062x over previous
//
#include <hip/hip_runtime.h>
#include <hip/hip_bf16.h>
#include <math.h>

#define B_ 16
#define C_ 64
#define N_ 4096   // 64*64 pixels
#define M_ 1024   // 32*32 pooled keys

typedef __attribute__((ext_vector_type(8))) short v8s;   // 8 bf16 (4 VGPRs)
typedef __attribute__((ext_vector_type(4))) float v4f;   // 4 fp32 acc

__device__ inline unsigned short f2bf(float f) {
    __hip_bfloat16 h = __float2bfloat16(f);
    return *(unsigned short*)&h;
}
__device__ inline unsigned pack2bf(float a, float b) {
    return (unsigned)f2bf(a) | ((unsigned)f2bf(b) << 16);
}
__device__ inline v8s cvt8(float4 a, float4 b) {
    union { v8s v; unsigned u[4]; } r;
    r.u[0] = pack2bf(a.x, a.y);
    r.u[1] = pack2bf(a.z, a.w);
    r.u[2] = pack2bf(b.x, b.y);
    r.u[3] = pack2bf(b.z, b.w);
    return r.v;
}

// ---------------------------------------------------------------------------
// Kernel 1 (round 5): same MFMA conv structure as round 4, but 2x occupancy.
// Round 4 ran grid=256 -> exactly 1 wave/SIMD: every strided x-load latency
// fully exposed. Now: block = one ROW-PAIR (2 image rows), 4 waves, each wave
// does half a row (2 n-tiles of 16 px); grid = 16 batches x 32 row-pairs =
// 512 blocks -> 2 blocks/CU -> 2 waves/SIMD. Weights still live in
// A-fragments loaded once. m-tiles: 0=[theta(8);phi(8)], 1=g[0..15],
// 2=g[16..31]. MFMA layouts (measured m89/m91): A[m=l15][k=l4*8+j],
// B[k=l4*8+j][n=l15], C/D: col(n)=l15, row(m)=l4*4+reg.
// ---------------------------------------------------------------------------
#define SP2 66   // sPool row stride (floats): ch-stride 2*66=132 = 4 banks;
                 // l4 groups land 16 banks apart -> 2-way (free, m136)

__global__ __launch_bounds__(256, 2) void conv_pool_k(
    const float* __restrict__ x,
    const float* __restrict__ Wt, const float* __restrict__ bt,
    const float* __restrict__ Wp, const float* __restrict__ bp,
    const float* __restrict__ Wg, const float* __restrict__ bg,
    unsigned short* __restrict__ thetaT,
    unsigned short* __restrict__ phiT,
    unsigned short* __restrict__ gcm)
{
    __shared__ float sPool[80 * SP2];   // 40 ch x 2 rows = 80 rows, 21.1 KB

    const int tid  = threadIdx.x;
    const int lane = tid & 63;
    const int wid  = tid >> 6;
    const int l15  = lane & 15;
    const int l4   = lane >> 4;

    const int b  = blockIdx.x >> 5;
    const int y0 = (blockIdx.x & 31) << 1;   // first of 2 image rows
    const int y  = y0 + (wid >> 1);          // this wave's row
    const int xh = (wid & 1) * 32;           // this wave's half-row

    // --- A-fragments: weights, 3 m-tiles x 2 k-halves (bf16, loaded once)
    const float* row0 = (l15 < 8) ? (Wt + l15 * 64) : (Wp + (l15 - 8) * 64);
    const float* row1 = Wg + l15 * 64;
    const float* row2 = Wg + (16 + l15) * 64;
    v8s afrag[3][2];
    #pragma unroll
    for (int kh = 0; kh < 2; ++kh) {
        const int c0 = kh * 32 + l4 * 8;
        afrag[0][kh] = cvt8(*(const float4*)(row0 + c0), *(const float4*)(row0 + c0 + 4));
        afrag[1][kh] = cvt8(*(const float4*)(row1 + c0), *(const float4*)(row1 + c0 + 4));
        afrag[2][kh] = cvt8(*(const float4*)(row2 + c0), *(const float4*)(row2 + c0 + 4));
    }

    // --- accumulators init = bias (C-layout: row o = l4*4+r)
    v4f acc[2][3];
    {
        float bv[3][4];
        #pragma unroll
        for (int r = 0; r < 4; ++r) {
            const int o = l4 * 4 + r;               // 0..15
            bv[0][r] = (o < 8) ? bt[o] : bp[o - 8];
            bv[1][r] = bg[o];
            bv[2][r] = bg[16 + o];
        }
        #pragma unroll
        for (int nt = 0; nt < 2; ++nt)
            #pragma unroll
            for (int t = 0; t < 3; ++t) {
                v4f a; a[0] = bv[t][0]; a[1] = bv[t][1];
                a[2] = bv[t][2]; a[3] = bv[t][3];
                acc[nt][t] = a;
            }
    }

    // --- main GEMM: 2 n-tiles x 2 k-halves x 3 m-tiles
    const float* xb = x + (size_t)b * C_ * N_ + y * 64;
    #pragma unroll
    for (int nt = 0; nt < 2; ++nt) {
        const int n0 = xh + nt * 16 + l15;
        #pragma unroll
        for (int kh = 0; kh < 2; ++kh) {
            const int cb = kh * 32 + l4 * 8;
            float f[8];
            #pragma unroll
            for (int j = 0; j < 8; ++j) f[j] = xb[(size_t)(cb + j) * N_ + n0];
            union { v8s v; unsigned u[4]; } bf;
            #pragma unroll
            for (int j = 0; j < 4; ++j) bf.u[j] = pack2bf(f[2*j], f[2*j+1]);
            #pragma unroll
            for (int t = 0; t < 3; ++t)
                acc[nt][t] = __builtin_amdgcn_mfma_f32_16x16x32_bf16(
                    afrag[t][kh], bf.v, acc[nt][t], 0, 0, 0);
        }
    }

    // --- theta: straight from C-regs (rows 0..7 of m-tile 0 = lanes l4<2)
    #pragma unroll
    for (int nt = 0; nt < 2; ++nt) {
        if (l4 < 2) {
            const int n = y * 64 + xh + nt * 16 + l15;
            const unsigned lo = pack2bf(acc[nt][0][0], acc[nt][0][1]);
            const unsigned hi = pack2bf(acc[nt][0][2], acc[nt][0][3]);
            *(uint2*)(thetaT + ((size_t)b * N_ + n) * 8 + l4 * 4) = make_uint2(lo, hi);
        }
    }

    // --- stage phi/g to LDS for pooling: row index = ch*2 + (image row in pair)
    {
        const int rr = wid >> 1;   // 0/1: which row of the pair
        #pragma unroll
        for (int nt = 0; nt < 2; ++nt) {
            const int px = xh + nt * 16 + l15;      // 0..63
            if (l4 >= 2) {                          // phi: ch = (l4-2)*4 + r
                #pragma unroll
                for (int r = 0; r < 4; ++r)
                    sPool[(((l4 - 2) * 4 + r) * 2 + rr) * SP2 + px] = acc[nt][0][r];
            }
            #pragma unroll
            for (int r = 0; r < 4; ++r) {
                sPool[((8  + l4 * 4 + r) * 2 + rr) * SP2 + px] = acc[nt][1][r];
                sPool[((24 + l4 * 4 + r) * 2 + rr) * SP2 + px] = acc[nt][2][r];
            }
        }
    }
    __syncthreads();

    // --- 2x2 maxpool + store: 40 ch x 32 pooled px per block
    {
        const int pc  = tid & 31;          // pooled col
        const int grp = tid >> 5;          // 8 groups x 5 channels
        const int mg  = (y0 >> 1) * 32 + pc;
        #pragma unroll
        for (int i = 0; i < 5; ++i) {
            const int ch = grp * 5 + i;
            const float* s0 = sPool + (ch * 2 + 0) * SP2 + pc * 2;
            const float* s1 = sPool + (ch * 2 + 1) * SP2 + pc * 2;
            const float v = fmaxf(fmaxf(s0[0], s0[1]), fmaxf(s1[0], s1[1]));
            if (ch < 8) phiT[((size_t)b * M_ + mg) * 8 + ch] = f2bf(v);
            else        gcm[((size_t)(b * 32 + ch - 8)) * M_ + mg] = f2bf(v);
        }
    }
}

// ---------------------------------------------------------------------------
// Kernel 2 (round 5): MFMA flash attention + fused output conv + residual.
// Same math as round 2-4 (passed, absmax 0.0156) but 2x occupancy: 64 queries
// per block (16 q/wave, qs loop removed), grid = 16 x 64 = 1024 blocks.
// LDS 34.8 KB/block -> 4 blocks/CU = 4 waves/SIMD (launch_bounds(256,4)).
// Per-wave serial chain (S-MFMA -> exp -> pack -> sP -> read -> O-MFMA)
// halves in length and 4 independent chains/SIMD interleave.
// ---------------------------------------------------------------------------
#define GPAD   264   // sgT row stride (shorts): b128 reads spread evenly
#define PROW   40    // sP row stride (shorts): 80 B, 16B-aligned

__global__ __launch_bounds__(256, 4) void attn_k(
    const float* __restrict__ x,
    const unsigned short* __restrict__ thetaT,
    const unsigned short* __restrict__ phiT,
    const unsigned short* __restrict__ gcm,
    const float* __restrict__ Wo, const float* __restrict__ bo,
    const float* __restrict__ gammap,
    float* __restrict__ out)
{
    __shared__ unsigned short sphi[2][128][8];   // 4 KB  even/odd key split
    __shared__ unsigned short sgT[32][GPAD];     // 16.5 KB [c][m]
    __shared__ unsigned short sP[4][16][PROW];   // 5 KB per-wave P slabs
    __shared__ float sO[32][68];                 // 8.7 KB [c][q] epilogue

    const int tid  = threadIdx.x;
    const int lane = tid & 63;
    const int wid  = tid >> 6;
    const int l15  = lane & 15;
    const int l4   = lane >> 4;

    const int b  = blockIdx.x >> 6;
    const int q0 = (blockIdx.x & 63) << 6;   // 64 queries per block
    const int qw = q0 + wid * 16;            // this wave's first query

    // theta A-fragment (K=8 real, rest zero): lanes 16..63 are zero
    v8s aT;
    {
        v8s z = {};
        aT = z;
        if (l4 == 0)
            aT = *(const v8s*)(thetaT + ((size_t)b * N_ + qw + l15) * 8);
    }

    v4f accO[2];
    { v4f z = {}; accO[0] = z; accO[1] = z; }
    float lsum[4] = {0.f, 0.f, 0.f, 0.f};
    const v4f zf = {};

    for (int t = 0; t < 4; ++t) {            // 4 key tiles of 256
        __syncthreads();
        // stage phi tile, split even/odd keys
        {
            const uint4 v = *(const uint4*)(phiT + ((size_t)b * M_ + t * 256 + tid) * 8);
            *(uint4*)&sphi[tid & 1][tid >> 1][0] = v;
        }
        // stage g tile channel-major [c][m]
        {
            const int row = tid >> 3, ch = tid & 7;
            const uint4* src = (const uint4*)(gcm + ((size_t)(b * 32 + row)) * M_ + t * 256 + ch * 32);
            uint4* dst = (uint4*)&sgT[row][ch * 32];
            dst[0] = src[0]; dst[1] = src[1]; dst[2] = src[2]; dst[3] = src[3];
        }
        __syncthreads();

        for (int cc = 0; cc < 8; ++cc) {     // 32-key chunks
            // phi B-frags: subtile kt covers keys {cc*32 + 2n + kt}
            v8s bph0, bph1;
            { v8s z = {}; bph0 = z; bph1 = z; }
            if (l4 == 0) {
                bph0 = *(const v8s*)&sphi[0][cc * 16 + l15][0];
                bph1 = *(const v8s*)&sphi[1][cc * 16 + l15][0];
            }
            // S tile + exp + pack into per-wave sP slab (natural key order)
            {
                v4f s0 = __builtin_amdgcn_mfma_f32_16x16x32_bf16(aT, bph0, zf, 0, 0, 0);
                v4f s1 = __builtin_amdgcn_mfma_f32_16x16x32_bf16(aT, bph1, zf, 0, 0, 0);
                #pragma unroll
                for (int r = 0; r < 4; ++r) {
                    float e0 = __expf(s0[r]);   // key cc*32 + 2*l15
                    float e1 = __expf(s1[r]);   // key cc*32 + 2*l15 + 1
                    lsum[r] += e0 + e1;
                    *(unsigned*)&sP[wid][l4 * 4 + r][2 * l15] = pack2bf(e0, e1);
                }
            }
            // G B-frags
            v8s bg0 = *(const v8s*)&sgT[l15     ][cc * 32 + l4 * 8];
            v8s bg1 = *(const v8s*)&sgT[16 + l15][cc * 32 + l4 * 8];
            // P A-frag (round-trip) + O MFMAs
            {
                v8s ap = *(const v8s*)&sP[wid][l15][l4 * 8];
                accO[0] = __builtin_amdgcn_mfma_f32_16x16x32_bf16(ap, bg0, accO[0], 0, 0, 0);
                accO[1] = __builtin_amdgcn_mfma_f32_16x16x32_bf16(ap, bg1, accO[1], 0, 0, 0);
            }
        }
    }

    // softmax denominators: reduce across the 16 key-columns (lane&15 groups)
    float rl[4];
    #pragma unroll
    for (int r = 0; r < 4; ++r) {
        float v = lsum[r];
        v += __shfl_xor(v, 1);
        v += __shfl_xor(v, 2);
        v += __shfl_xor(v, 4);
        v += __shfl_xor(v, 8);
        rl[r] = 1.0f / v;
    }

    // write normalized O to LDS [c][q]
    #pragma unroll
    for (int ct = 0; ct < 2; ++ct)
        #pragma unroll
        for (int r = 0; r < 4; ++r)
            sO[ct * 16 + l15][wid * 16 + l4 * 4 + r] = accO[ct][r] * rl[r];
    __syncthreads();

    // epilogue: out = gamma*(Wo . O + bo) + x.  Wave-uniform oc set ->
    // Wo/bo via scalar loads; O column from LDS (conflict-free).
    {
        const int qq   = tid & 63;
        const int half = tid >> 6;          // oc 16*half .. 16*half+15
        const int n    = q0 + qq;
        float col[32];
        #pragma unroll
        for (int c = 0; c < 32; ++c) col[c] = sO[c][qq];
        const float gamma = *gammap;
        const float* xb = x   + ((size_t)(b * 64 + half * 16)) * N_ + n;
        float*       ob = out + ((size_t)(b * 64 + half * 16)) * N_ + n;
        #pragma unroll
        for (int j = 0; j < 16; ++j) {
            const int oc = half * 16 + j;
            const float* w = Wo + oc * 32;   // uniform -> s_load
            float r = 0.f;
            #pragma unroll
            for (int c = 0; c < 32; ++c) r = fmaf(w[c], col[c], r);
            ob[(size_t)j * N_] = gamma * (r + bo[oc]) + xb[(size_t)j * N_];
        }
    }
}

// ---------------------------------------------------------------------------
extern "C" void kernel_launch(void* const* d_in, const int* in_sizes, int n_in,
                              void* d_out, int out_size, void* d_ws, size_t ws_size,
                              hipStream_t stream) {
    const float* x  = (const float*)d_in[0];
    const float* Wt = (const float*)d_in[1];
    const float* bt = (const float*)d_in[2];
    const float* Wp = (const float*)d_in[3];
    const float* bp = (const float*)d_in[4];
    const float* Wg = (const float*)d_in[5];
    const float* bg = (const float*)d_in[6];
    const float* Wo = (const float*)d_in[7];
    const float* bo = (const float*)d_in[8];
    const float* gm = (const float*)d_in[9];
    float* out = (float*)d_out;

    // workspace (bf16): thetaT [16][4096][8] | phiT [16][1024][8] | gcm [16][32][1024]
    unsigned short* thetaT = (unsigned short*)d_ws;
    unsigned short* phiT   = thetaT + (size_t)B_ * N_ * 8;
    unsigned short* gcm    = phiT   + (size_t)B_ * M_ * 8;

    hipLaunchKernelGGL(conv_pool_k, dim3(512), dim3(256), 0, stream,
                       x, Wt, bt, Wp, bp, Wg, bg, thetaT, phiT, gcm);
    hipLaunchKernelGGL(attn_k, dim3(1024), dim3(256), 0, stream,
                       x, thetaT, phiT, gcm, Wo, bo, gm, out);
}